// Round 1
// baseline (1036.115 us; speedup 1.0000x reference)
//
#include <hip/hip_runtime.h>
#include <math.h>
#include <stdint.h>

#define NEG_SLOPE 0.2f

__device__ __forceinline__ float leaky(float a) { return a > 0.f ? a : NEG_SLOPE * a; }

// monotonic int-punned float atomic max (works for mixed signs; init to -inf)
__device__ __forceinline__ void atomicMaxF(float* addr, float val) {
    int bits = __float_as_int(val);
    if (bits >= 0) atomicMax((int*)addr, bits);
    else atomicMin((unsigned int*)addr, (unsigned int)bits);
}

// ---------------- edge MLP + edge attention terms ----------------
__global__ void k_edge(const float* __restrict__ ef,
                       const float* __restrict__ Em1, const float* __restrict__ eb1,
                       const float* __restrict__ Em2, const float* __restrict__ eb2,
                       const float* __restrict__ We1, const float* __restrict__ ae1,
                       const float* __restrict__ We2, const float* __restrict__ ae2,
                       float* __restrict__ ea1, float* __restrict__ ea2, int E) {
    int e = blockIdx.x * blockDim.x + threadIdx.x;
    if (e >= E) return;
    float f0 = ef[e*3+0], f1 = ef[e*3+1], f2 = ef[e*3+2];
    float t0 = fmaxf(f0*Em1[0]+f1*Em1[3]+f2*Em1[6]+eb1[0], 0.f);
    float t1 = fmaxf(f0*Em1[1]+f1*Em1[4]+f2*Em1[7]+eb1[1], 0.f);
    float t2 = fmaxf(f0*Em1[2]+f1*Em1[5]+f2*Em1[8]+eb1[2], 0.f);
    float u0 = t0*Em2[0]+t1*Em2[3]+t2*Em2[6]+eb2[0];
    float u1 = t0*Em2[1]+t1*Em2[4]+t2*Em2[7]+eb2[1];
    float u2 = t0*Em2[2]+t1*Em2[5]+t2*Em2[8]+eb2[2];
    float a0=0.f,a1=0.f,a2=0.f,a3=0.f;
    #pragma unroll
    for (int k=0;k<64;k++) {
        float eek = u0*We1[k] + u1*We1[64+k] + u2*We1[128+k];
        float v = eek * ae1[k];
        if (k<16) a0+=v; else if (k<32) a1+=v; else if (k<48) a2+=v; else a3+=v;
    }
    ea1[e*4+0]=a0; ea1[e*4+1]=a1; ea1[e*4+2]=a2; ea1[e*4+3]=a3;
    float g0 = u0*We2[0]+u1*We2[2]+u2*We2[4];
    float g1 = u0*We2[1]+u1*We2[3]+u2*We2[5];
    ea2[e] = g0*ae2[0]+g1*ae2[1];
}

// ---------------- layer1 node projection: xs1 = x@W1, a_src1, a_dst1 ----------------
__global__ __launch_bounds__(256) void k_proj1(const float* __restrict__ x, const float* __restrict__ W1,
        const float* __restrict__ as1, const float* __restrict__ ad1,
        float* __restrict__ xs1, float* __restrict__ as1v, float* __restrict__ ad1v, int N) {
    __shared__ float xr[4][128];
    int wave = threadIdx.x >> 6, lane = threadIdx.x & 63;
    int n = blockIdx.x * 4 + wave;
    if (n >= N) n = N - 1;   // duplicates write identical values (pure), safe
    xr[wave][lane]      = x[(size_t)n*128 + lane];
    xr[wave][lane + 64] = x[(size_t)n*128 + lane + 64];
    __syncthreads();
    float acc = 0.f;
    #pragma unroll 8
    for (int k=0;k<128;k++) acc = fmaf(xr[wave][k], W1[k*64+lane], acc);
    xs1[(size_t)n*64+lane] = acc;
    float ps = acc*as1[lane], pd = acc*ad1[lane];
    #pragma unroll
    for (int off=8; off>=1; off>>=1) { ps += __shfl_xor(ps,off,16); pd += __shfl_xor(pd,off,16); }
    if ((lane&15)==0) { int h = lane>>4; as1v[n*4+h]=ps; ad1v[n*4+h]=pd; }
}

__global__ void k_fill(float* __restrict__ p, float v, int n) {
    int i = blockIdx.x*blockDim.x+threadIdx.x;
    if (i < n) p[i] = v;
}

// ---------------- layer1 softmax passes ----------------
__global__ void k_amax1(const int* __restrict__ src, const int* __restrict__ dst,
                        const float* __restrict__ as1v, const float* __restrict__ ad1v,
                        const float* __restrict__ ea1, float* __restrict__ mx1, int E) {
    int i = blockIdx.x*blockDim.x+threadIdx.x;       // i = e*4+h
    if (i >= E*4) return;
    int e = i>>2, h = i&3;
    int s = src[e], d = dst[e];
    float a = leaky(as1v[s*4+h] + ad1v[d*4+h] + ea1[i]);
    atomicMaxF(&mx1[d*4+h], a);
}

__global__ void k_asum1(const int* __restrict__ src, const int* __restrict__ dst,
                        const float* __restrict__ as1v, const float* __restrict__ ad1v,
                        const float* __restrict__ ea1, const float* __restrict__ mx1,
                        float* __restrict__ sm1, int E) {
    int i = blockIdx.x*blockDim.x+threadIdx.x;
    if (i >= E*4) return;
    int e = i>>2, h = i&3;
    int s = src[e], d = dst[e];
    float a = leaky(as1v[s*4+h] + ad1v[d*4+h] + ea1[i]);
    atomicAdd(&sm1[d*4+h], expf(a - mx1[d*4+h]));
}

__global__ void k_agg1(const int* __restrict__ src, const int* __restrict__ dst,
                       const float* __restrict__ as1v, const float* __restrict__ ad1v,
                       const float* __restrict__ ea1, const float* __restrict__ mx1,
                       const float* __restrict__ sm1, const float* __restrict__ xs1,
                       float* __restrict__ h1, int E) {
    int i = blockIdx.x*blockDim.x+threadIdx.x;       // i = e*64 + k
    if (i >= E*64) return;
    int e = i>>6, k = i&63, h = k>>4;
    int s = src[e], d = dst[e];
    float a = leaky(as1v[s*4+h] + ad1v[d*4+h] + ea1[e*4+h]);
    float coef = expf(a - mx1[d*4+h]) / (sm1[d*4+h] + 1e-16f);
    atomicAdd(&h1[(size_t)d*64+k], coef * xs1[(size_t)s*64+k]);
}

// ---------------- bias+ELU then layer2 projection ----------------
__global__ __launch_bounds__(256) void k_elu_proj2(float* __restrict__ h1, const float* __restrict__ b1,
        const float* __restrict__ W2, const float* __restrict__ as2, const float* __restrict__ ad2,
        float* __restrict__ xs2, float* __restrict__ as2v, float* __restrict__ ad2v, int N) {
    int wave = threadIdx.x >> 6, lane = threadIdx.x & 63;
    int n = blockIdx.x*4 + wave;
    if (n >= N) return;
    float v = h1[(size_t)n*64+lane] + b1[lane];
    v = v > 0.f ? v : (expf(v) - 1.f);
    h1[(size_t)n*64+lane] = v;
    float p0 = v*W2[lane*2+0], p1 = v*W2[lane*2+1];
    #pragma unroll
    for (int off=32; off>=1; off>>=1) { p0 += __shfl_xor(p0,off,64); p1 += __shfl_xor(p1,off,64); }
    if (lane == 0) {
        xs2[n*2+0] = p0; xs2[n*2+1] = p1;
        as2v[n] = p0*as2[0] + p1*as2[1];
        ad2v[n] = p0*ad2[0] + p1*ad2[1];
    }
}

// ---------------- layer2 softmax passes ----------------
__global__ void k_amax2(const int* __restrict__ src, const int* __restrict__ dst,
                        const float* __restrict__ as2v, const float* __restrict__ ad2v,
                        const float* __restrict__ ea2, float* __restrict__ mx2, int E) {
    int e = blockIdx.x*blockDim.x+threadIdx.x;
    if (e >= E) return;
    int s = src[e], d = dst[e];
    float a = leaky(as2v[s] + ad2v[d] + ea2[e]);
    atomicMaxF(&mx2[d], a);
}

__global__ void k_asum2(const int* __restrict__ src, const int* __restrict__ dst,
                        const float* __restrict__ as2v, const float* __restrict__ ad2v,
                        const float* __restrict__ ea2, const float* __restrict__ mx2,
                        float* __restrict__ sm2, int E) {
    int e = blockIdx.x*blockDim.x+threadIdx.x;
    if (e >= E) return;
    int s = src[e], d = dst[e];
    float a = leaky(as2v[s] + ad2v[d] + ea2[e]);
    atomicAdd(&sm2[d], expf(a - mx2[d]));
}

__global__ void k_prefill_out(float* __restrict__ out, const float* __restrict__ b2, int n2) {
    int i = blockIdx.x*blockDim.x+threadIdx.x;
    if (i < n2) out[i] = b2[i & 1];
}

__global__ void k_agg2(const int* __restrict__ src, const int* __restrict__ dst,
                       const float* __restrict__ as2v, const float* __restrict__ ad2v,
                       const float* __restrict__ ea2, const float* __restrict__ mx2,
                       const float* __restrict__ sm2, const float* __restrict__ xs2,
                       float* __restrict__ out, int E) {
    int e = blockIdx.x*blockDim.x+threadIdx.x;
    if (e >= E) return;
    int s = src[e], d = dst[e];
    float a = leaky(as2v[s] + ad2v[d] + ea2[e]);
    float coef = expf(a - mx2[d]) / (sm2[d] + 1e-16f);
    atomicAdd(&out[d*2+0], coef * xs2[s*2+0]);
    atomicAdd(&out[d*2+1], coef * xs2[s*2+1]);
}

extern "C" void kernel_launch(void* const* d_in, const int* in_sizes, int n_in,
                              void* d_out, int out_size, void* d_ws, size_t ws_size,
                              hipStream_t stream) {
    const float* x   = (const float*)d_in[0];
    const int*   ei  = (const int*)d_in[1];
    const float* ef  = (const float*)d_in[2];
    const float* Em1 = (const float*)d_in[3];
    const float* eb1 = (const float*)d_in[4];
    const float* Em2 = (const float*)d_in[5];
    const float* eb2 = (const float*)d_in[6];
    const float* W1  = (const float*)d_in[7];
    const float* as1 = (const float*)d_in[8];
    const float* ad1 = (const float*)d_in[9];
    const float* We1 = (const float*)d_in[10];
    const float* ae1 = (const float*)d_in[11];
    const float* b1  = (const float*)d_in[12];
    const float* W2  = (const float*)d_in[13];
    const float* as2 = (const float*)d_in[14];
    const float* ad2 = (const float*)d_in[15];
    const float* We2 = (const float*)d_in[16];
    const float* ae2 = (const float*)d_in[17];
    const float* b2  = (const float*)d_in[18];

    const int N = in_sizes[0] / 128;
    const int E = in_sizes[1] / 2;
    const int* srcp = ei;
    const int* dstp = ei + E;

    uintptr_t w = (uintptr_t)d_ws;
    auto alloc = [&](size_t bytes) -> float* {
        uintptr_t p = w; w += (bytes + 255) & ~(size_t)255; return (float*)p;
    };
    float* ea1  = alloc((size_t)E*4*sizeof(float));
    float* ea2  = alloc((size_t)E*sizeof(float));
    float* xs1  = alloc((size_t)N*64*sizeof(float));
    float* as1v = alloc((size_t)N*4*sizeof(float));
    float* ad1v = alloc((size_t)N*4*sizeof(float));
    float* mx1  = alloc((size_t)N*4*sizeof(float));
    float* sm1  = alloc((size_t)N*4*sizeof(float));
    float* h1   = alloc((size_t)N*64*sizeof(float));
    float* xs2  = alloc((size_t)N*2*sizeof(float));
    float* as2v = alloc((size_t)N*sizeof(float));
    float* ad2v = alloc((size_t)N*sizeof(float));
    float* mx2  = alloc((size_t)N*sizeof(float));
    float* sm2  = alloc((size_t)N*sizeof(float));

    const int B = 256;

    hipMemsetAsync(sm1, 0, (size_t)N*4*sizeof(float), stream);
    hipMemsetAsync(h1,  0, (size_t)N*64*sizeof(float), stream);
    hipMemsetAsync(sm2, 0, (size_t)N*sizeof(float), stream);
    k_fill<<<(N*4+B-1)/B, B, 0, stream>>>(mx1, -INFINITY, N*4);
    k_fill<<<(N+B-1)/B, B, 0, stream>>>(mx2, -INFINITY, N);

    k_edge<<<(E+B-1)/B, B, 0, stream>>>(ef, Em1, eb1, Em2, eb2, We1, ae1, We2, ae2, ea1, ea2, E);
    k_proj1<<<(N+3)/4, 256, 0, stream>>>(x, W1, as1, ad1, xs1, as1v, ad1v, N);

    k_amax1<<<(E*4+B-1)/B, B, 0, stream>>>(srcp, dstp, as1v, ad1v, ea1, mx1, E);
    k_asum1<<<(E*4+B-1)/B, B, 0, stream>>>(srcp, dstp, as1v, ad1v, ea1, mx1, sm1, E);
    {
        long long tot = (long long)E * 64;
        int grid = (int)((tot + B - 1) / B);
        k_agg1<<<grid, B, 0, stream>>>(srcp, dstp, as1v, ad1v, ea1, mx1, sm1, xs1, h1, E);
    }

    k_elu_proj2<<<(N+3)/4, 256, 0, stream>>>(h1, b1, W2, as2, ad2, xs2, as2v, ad2v, N);

    k_amax2<<<(E+B-1)/B, B, 0, stream>>>(srcp, dstp, as2v, ad2v, ea2, mx2, E);
    k_asum2<<<(E+B-1)/B, B, 0, stream>>>(srcp, dstp, as2v, ad2v, ea2, mx2, sm2, E);
    k_prefill_out<<<(N*2+B-1)/B, B, 0, stream>>>((float*)d_out, b2, N*2);
    k_agg2<<<(E+B-1)/B, B, 0, stream>>>(srcp, dstp, as2v, ad2v, ea2, mx2, sm2, xs2, (float*)d_out, E);
}

// Round 2
// 475.831 us; speedup vs baseline: 2.1775x; 2.1775x over previous
//
#include <hip/hip_runtime.h>
#include <math.h>
#include <stdint.h>

#define NEG_SLOPE 0.2f
#define SCAN_TILE 2048

__device__ __forceinline__ float leaky(float a) { return a > 0.f ? a : NEG_SLOPE * a; }

// ---------------- CSR build ----------------
__global__ void k_hist(const int* __restrict__ dst, int* __restrict__ deg, int E) {
    int e = blockIdx.x * blockDim.x + threadIdx.x;
    if (e < E) atomicAdd(&deg[dst[e]], 1);
}

__global__ __launch_bounds__(256) void k_scan_partial(const int* __restrict__ deg, int* __restrict__ tsum, int N) {
    __shared__ int sh[256];
    int b = blockIdx.x, t = threadIdx.x;
    int base = b * SCAN_TILE + t * 8;
    int s = 0;
    #pragma unroll
    for (int i = 0; i < 8; i++) { int idx = base + i; s += (idx < N) ? deg[idx] : 0; }
    sh[t] = s; __syncthreads();
    for (int o = 128; o > 0; o >>= 1) { if (t < o) sh[t] += sh[t + o]; __syncthreads(); }
    if (t == 0) tsum[b] = sh[0];
}

__global__ void k_scan_tsum(const int* __restrict__ tsum, int* __restrict__ toff,
                            int* __restrict__ rowptr, int nb, int N) {
    if (threadIdx.x == 0 && blockIdx.x == 0) {
        int run = 0;
        for (int i = 0; i < nb; i++) { toff[i] = run; run += tsum[i]; }
        rowptr[N] = run;
    }
}

__global__ __launch_bounds__(256) void k_scan_final(const int* __restrict__ deg, const int* __restrict__ toff,
        int* __restrict__ rowptr, int* __restrict__ cursor, int N) {
    __shared__ int sh[256];
    int b = blockIdx.x, t = threadIdx.x;
    int base = b * SCAN_TILE + t * 8;
    int v[8]; int s = 0;
    #pragma unroll
    for (int i = 0; i < 8; i++) { int idx = base + i; v[i] = (idx < N) ? deg[idx] : 0; s += v[i]; }
    sh[t] = s; __syncthreads();
    for (int o = 1; o < 256; o <<= 1) {
        int u = (t >= o) ? sh[t - o] : 0;
        __syncthreads();
        sh[t] += u;
        __syncthreads();
    }
    int run = sh[t] - s + toff[b];   // exclusive prefix of this thread's first element
    #pragma unroll
    for (int i = 0; i < 8; i++) {
        int idx = base + i;
        if (idx < N) { rowptr[idx] = run; cursor[idx] = run; run += v[i]; }
    }
}

// ---------------- edge MLP + attention terms, scattered into CSR order ----------------
__global__ void k_edge_scatter(const float* __restrict__ ef,
                       const float* __restrict__ Em1, const float* __restrict__ eb1,
                       const float* __restrict__ Em2, const float* __restrict__ eb2,
                       const float* __restrict__ We1, const float* __restrict__ ae1,
                       const float* __restrict__ We2, const float* __restrict__ ae2,
                       const int* __restrict__ src, const int* __restrict__ dst,
                       int* __restrict__ cursor, int* __restrict__ csr_src,
                       float4* __restrict__ csr_ea1, float* __restrict__ csr_ea2, int E) {
    int e = blockIdx.x * blockDim.x + threadIdx.x;
    if (e >= E) return;
    float f0 = ef[e*3+0], f1 = ef[e*3+1], f2 = ef[e*3+2];
    float t0 = fmaxf(f0*Em1[0]+f1*Em1[3]+f2*Em1[6]+eb1[0], 0.f);
    float t1 = fmaxf(f0*Em1[1]+f1*Em1[4]+f2*Em1[7]+eb1[1], 0.f);
    float t2 = fmaxf(f0*Em1[2]+f1*Em1[5]+f2*Em1[8]+eb1[2], 0.f);
    float u0 = t0*Em2[0]+t1*Em2[3]+t2*Em2[6]+eb2[0];
    float u1 = t0*Em2[1]+t1*Em2[4]+t2*Em2[7]+eb2[1];
    float u2 = t0*Em2[2]+t1*Em2[5]+t2*Em2[8]+eb2[2];
    float a0=0.f,a1=0.f,a2=0.f,a3=0.f;
    #pragma unroll
    for (int k=0;k<64;k++) {
        float eek = u0*We1[k] + u1*We1[64+k] + u2*We1[128+k];
        float v = eek * ae1[k];
        if (k<16) a0+=v; else if (k<32) a1+=v; else if (k<48) a2+=v; else a3+=v;
    }
    float g0 = u0*We2[0]+u1*We2[2]+u2*We2[4];
    float g1 = u0*We2[1]+u1*We2[3]+u2*We2[5];
    int d = dst[e];
    int pos = atomicAdd(&cursor[d], 1);
    csr_src[pos] = src[e];
    csr_ea1[pos] = make_float4(a0, a1, a2, a3);
    csr_ea2[pos] = g0*ae2[0] + g1*ae2[1];
}

// ---------------- layer1 node projection: xs1 = x@W1, a_src1, a_dst1 ----------------
__global__ __launch_bounds__(256) void k_proj1(const float* __restrict__ x, const float* __restrict__ W1,
        const float* __restrict__ as1, const float* __restrict__ ad1,
        float* __restrict__ xs1, float* __restrict__ as1v, float* __restrict__ ad1v, int N) {
    __shared__ float xr[4][128];
    int wave = threadIdx.x >> 6, lane = threadIdx.x & 63;
    int n = blockIdx.x * 4 + wave;
    if (n >= N) n = N - 1;   // duplicates write identical values (pure), safe
    xr[wave][lane]      = x[(size_t)n*128 + lane];
    xr[wave][lane + 64] = x[(size_t)n*128 + lane + 64];
    __syncthreads();
    float acc = 0.f;
    #pragma unroll 8
    for (int k=0;k<128;k++) acc = fmaf(xr[wave][k], W1[k*64+lane], acc);
    xs1[(size_t)n*64+lane] = acc;
    float ps = acc*as1[lane], pd = acc*ad1[lane];
    #pragma unroll
    for (int off=8; off>=1; off>>=1) { ps += __shfl_xor(ps,off,16); pd += __shfl_xor(pd,off,16); }
    if ((lane&15)==0) { int h = lane>>4; as1v[n*4+h]=ps; ad1v[n*4+h]=pd; }
}

// ---------------- fused layer1: softmax + aggregation, one wave per node ----------------
__global__ __launch_bounds__(256) void k_gat1(
        const int* __restrict__ rowptr, const int* __restrict__ csr_src,
        const float4* __restrict__ csr_ea1,
        const float* __restrict__ as1v, const float* __restrict__ ad1v,
        const float* __restrict__ xs1, float* __restrict__ h1, int N) {
    int wave = threadIdx.x >> 6, lane = threadIdx.x & 63;
    int d = blockIdx.x * 4 + wave;
    if (d >= N) return;
    int beg = rowptr[d], end = rowptr[d+1];
    int jj = lane >> 2, hh = lane & 3;          // pass layout: 16 edges x 4 heads
    float adh = ad1v[d*4 + hh];
    // ---- pass A: online per-head max & sum ----
    float mx = -INFINITY, sm = 0.f;
    for (int off = beg; off < end; off += 16) {
        int j = off + jj;
        float a = -INFINITY;
        if (j < end) {
            int s = csr_src[j];
            float4 ea = csr_ea1[j];
            float eah = hh==0 ? ea.x : hh==1 ? ea.y : hh==2 ? ea.z : ea.w;
            a = leaky(as1v[s*4+hh] + adh + eah);
        }
        float cm = a;
        cm = fmaxf(cm, __shfl_xor(cm, 4, 64));
        cm = fmaxf(cm, __shfl_xor(cm, 8, 64));
        cm = fmaxf(cm, __shfl_xor(cm, 16, 64));
        cm = fmaxf(cm, __shfl_xor(cm, 32, 64));
        float nm = fmaxf(mx, cm);
        float w = (j < end) ? __expf(a - nm) : 0.f;
        float cs = w;
        cs += __shfl_xor(cs, 4, 64);
        cs += __shfl_xor(cs, 8, 64);
        cs += __shfl_xor(cs, 16, 64);
        cs += __shfl_xor(cs, 32, 64);
        sm = sm * __expf(mx - nm) + cs;         // exp(-inf)=0 handles first chunk
        mx = nm;
    }
    float inv = 1.f / (sm + 1e-16f);
    // ---- pass B: aggregate; lane = output channel k ----
    int k = lane, hk = k >> 4;
    float acc = 0.f;
    for (int off = beg; off < end; off += 16) {
        int j = off + jj;
        float w = 0.f; int s = 0;
        if (j < end) {
            s = csr_src[j];
            float4 ea = csr_ea1[j];
            float eah = hh==0 ? ea.x : hh==1 ? ea.y : hh==2 ? ea.z : ea.w;
            float a = leaky(as1v[s*4+hh] + adh + eah);
            w = __expf(a - mx) * inv;           // per (edge jj, head hh)
        }
        int lim = min(16, end - off);
        for (int t = 0; t < lim; ++t) {
            float wt = __shfl(w, t*4 + hk, 64); // weight of edge t for my head
            int st   = __shfl(s, t*4, 64);      // src node of edge t
            acc = fmaf(wt, xs1[(size_t)st*64 + k], acc);  // coalesced 256B row
        }
    }
    h1[(size_t)d*64 + k] = acc;
}

// ---------------- bias+ELU then layer2 projection ----------------
__global__ __launch_bounds__(256) void k_elu_proj2(float* __restrict__ h1, const float* __restrict__ b1,
        const float* __restrict__ W2, const float* __restrict__ as2, const float* __restrict__ ad2,
        float* __restrict__ xs2, float* __restrict__ as2v, float* __restrict__ ad2v, int N) {
    int wave = threadIdx.x >> 6, lane = threadIdx.x & 63;
    int n = blockIdx.x*4 + wave;
    if (n >= N) return;
    float v = h1[(size_t)n*64+lane] + b1[lane];
    v = v > 0.f ? v : (expf(v) - 1.f);
    h1[(size_t)n*64+lane] = v;
    float p0 = v*W2[lane*2+0], p1 = v*W2[lane*2+1];
    #pragma unroll
    for (int off=32; off>=1; off>>=1) { p0 += __shfl_xor(p0,off,64); p1 += __shfl_xor(p1,off,64); }
    if (lane == 0) {
        xs2[n*2+0] = p0; xs2[n*2+1] = p1;
        as2v[n] = p0*as2[0] + p1*as2[1];
        ad2v[n] = p0*ad2[0] + p1*ad2[1];
    }
}

// ---------------- fused layer2: 16 lanes per node ----------------
__global__ __launch_bounds__(256) void k_gat2(
        const int* __restrict__ rowptr, const int* __restrict__ csr_src,
        const float* __restrict__ csr_ea2,
        const float* __restrict__ as2v, const float* __restrict__ ad2v,
        const float* __restrict__ xs2, const float* __restrict__ b2,
        float* __restrict__ out, int N) {
    int t = blockIdx.x * blockDim.x + threadIdx.x;
    int d = t >> 4, j16 = t & 15;
    if (d >= N) return;
    int beg = rowptr[d], end = rowptr[d+1];
    float add = ad2v[d];
    float mx = -INFINITY, sm = 0.f;
    for (int off = beg; off < end; off += 16) {
        int j = off + j16;
        float a = -INFINITY;
        if (j < end) a = leaky(as2v[csr_src[j]] + add + csr_ea2[j]);
        float cm = a;
        #pragma unroll
        for (int o = 1; o < 16; o <<= 1) cm = fmaxf(cm, __shfl_xor(cm, o, 16));
        float nm = fmaxf(mx, cm);
        float w = (j < end) ? __expf(a - nm) : 0.f;
        float cs = w;
        #pragma unroll
        for (int o = 1; o < 16; o <<= 1) cs += __shfl_xor(cs, o, 16);
        sm = sm * __expf(mx - nm) + cs;
        mx = nm;
    }
    float inv = 1.f / (sm + 1e-16f);
    float p0 = 0.f, p1 = 0.f;
    for (int off = beg; off < end; off += 16) {
        int j = off + j16;
        if (j < end) {
            int s = csr_src[j];
            float a = leaky(as2v[s] + add + csr_ea2[j]);
            float w = __expf(a - mx) * inv;
            p0 = fmaf(w, xs2[s*2+0], p0);
            p1 = fmaf(w, xs2[s*2+1], p1);
        }
    }
    #pragma unroll
    for (int o = 1; o < 16; o <<= 1) { p0 += __shfl_xor(p0, o, 16); p1 += __shfl_xor(p1, o, 16); }
    if (j16 == 0) { out[d*2+0] = p0 + b2[0]; out[d*2+1] = p1 + b2[1]; }
}

extern "C" void kernel_launch(void* const* d_in, const int* in_sizes, int n_in,
                              void* d_out, int out_size, void* d_ws, size_t ws_size,
                              hipStream_t stream) {
    const float* x   = (const float*)d_in[0];
    const int*   ei  = (const int*)d_in[1];
    const float* ef  = (const float*)d_in[2];
    const float* Em1 = (const float*)d_in[3];
    const float* eb1 = (const float*)d_in[4];
    const float* Em2 = (const float*)d_in[5];
    const float* eb2 = (const float*)d_in[6];
    const float* W1  = (const float*)d_in[7];
    const float* as1 = (const float*)d_in[8];
    const float* ad1 = (const float*)d_in[9];
    const float* We1 = (const float*)d_in[10];
    const float* ae1 = (const float*)d_in[11];
    const float* b1  = (const float*)d_in[12];
    const float* W2  = (const float*)d_in[13];
    const float* as2 = (const float*)d_in[14];
    const float* ad2 = (const float*)d_in[15];
    const float* We2 = (const float*)d_in[16];
    const float* ae2 = (const float*)d_in[17];
    const float* b2  = (const float*)d_in[18];

    const int N = in_sizes[0] / 128;
    const int E = in_sizes[1] / 2;
    const int* srcp = ei;
    const int* dstp = ei + E;

    uintptr_t w = (uintptr_t)d_ws;
    auto alloc = [&](size_t bytes) -> void* {
        uintptr_t p = w; w += (bytes + 255) & ~(size_t)255; return (void*)p;
    };
    const int nb = (N + SCAN_TILE - 1) / SCAN_TILE;
    int*    deg     = (int*)alloc((size_t)N * sizeof(int));
    int*    cursor  = (int*)alloc((size_t)N * sizeof(int));
    int*    rowptr  = (int*)alloc(((size_t)N + 1) * sizeof(int));
    int*    tsum    = (int*)alloc((size_t)nb * sizeof(int));
    int*    toff    = (int*)alloc((size_t)(nb + 1) * sizeof(int));
    int*    csr_src = (int*)alloc((size_t)E * sizeof(int));
    float4* csr_ea1 = (float4*)alloc((size_t)E * sizeof(float4));
    float*  csr_ea2 = (float*)alloc((size_t)E * sizeof(float));
    float*  xs1     = (float*)alloc((size_t)N * 64 * sizeof(float));
    float*  as1v    = (float*)alloc((size_t)N * 4 * sizeof(float));
    float*  ad1v    = (float*)alloc((size_t)N * 4 * sizeof(float));
    float*  h1      = (float*)alloc((size_t)N * 64 * sizeof(float));
    float*  xs2     = (float*)alloc((size_t)N * 2 * sizeof(float));
    float*  as2v    = (float*)alloc((size_t)N * sizeof(float));
    float*  ad2v    = (float*)alloc((size_t)N * sizeof(float));

    const int B = 256;

    hipMemsetAsync(deg, 0, (size_t)N * sizeof(int), stream);
    k_hist<<<(E+B-1)/B, B, 0, stream>>>(dstp, deg, E);
    k_scan_partial<<<nb, 256, 0, stream>>>(deg, tsum, N);
    k_scan_tsum<<<1, 64, 0, stream>>>(tsum, toff, rowptr, nb, N);
    k_scan_final<<<nb, 256, 0, stream>>>(deg, toff, rowptr, cursor, N);
    k_edge_scatter<<<(E+B-1)/B, B, 0, stream>>>(ef, Em1, eb1, Em2, eb2, We1, ae1, We2, ae2,
                                                srcp, dstp, cursor, csr_src, csr_ea1, csr_ea2, E);
    k_proj1<<<(N+3)/4, 256, 0, stream>>>(x, W1, as1, ad1, xs1, as1v, ad1v, N);
    k_gat1<<<(N+3)/4, 256, 0, stream>>>(rowptr, csr_src, csr_ea1, as1v, ad1v, xs1, h1, N);
    k_elu_proj2<<<(N+3)/4, 256, 0, stream>>>(h1, b1, W2, as2, ad2, xs2, as2v, ad2v, N);
    k_gat2<<<(N*16+B-1)/B, B, 0, stream>>>(rowptr, csr_src, csr_ea2, as2v, ad2v, xs2, b2, (float*)d_out, N);
}

// Round 3
// 408.244 us; speedup vs baseline: 2.5380x; 1.1656x over previous
//
#include <hip/hip_runtime.h>
#include <hip/hip_fp16.h>
#include <math.h>
#include <stdint.h>

#define NEG_SLOPE 0.2f
#define SCAN_TILE 2048

__device__ __forceinline__ float leaky(float a) { return a > 0.f ? a : NEG_SLOPE * a; }

// ---------------- CSR build ----------------
__global__ void k_hist(const int* __restrict__ dst, int* __restrict__ deg, int E) {
    int e = blockIdx.x * blockDim.x + threadIdx.x;
    if (e < E) atomicAdd(&deg[dst[e]], 1);
}

__global__ __launch_bounds__(256) void k_scan_partial(const int* __restrict__ deg, int* __restrict__ tsum, int N) {
    __shared__ int sh[256];
    int b = blockIdx.x, t = threadIdx.x;
    int base = b * SCAN_TILE + t * 8;
    int s = 0;
    #pragma unroll
    for (int i = 0; i < 8; i++) { int idx = base + i; s += (idx < N) ? deg[idx] : 0; }
    sh[t] = s; __syncthreads();
    for (int o = 128; o > 0; o >>= 1) { if (t < o) sh[t] += sh[t + o]; __syncthreads(); }
    if (t == 0) tsum[b] = sh[0];
}

__global__ void k_scan_tsum(const int* __restrict__ tsum, int* __restrict__ toff,
                            int* __restrict__ rowptr, int nb, int N) {
    if (threadIdx.x == 0 && blockIdx.x == 0) {
        int run = 0;
        for (int i = 0; i < nb; i++) { toff[i] = run; run += tsum[i]; }
        rowptr[N] = run;
    }
}

__global__ __launch_bounds__(256) void k_scan_final(const int* __restrict__ deg, const int* __restrict__ toff,
        int* __restrict__ rowptr, int* __restrict__ cursor, int N) {
    __shared__ int sh[256];
    int b = blockIdx.x, t = threadIdx.x;
    int base = b * SCAN_TILE + t * 8;
    int v[8]; int s = 0;
    #pragma unroll
    for (int i = 0; i < 8; i++) { int idx = base + i; v[i] = (idx < N) ? deg[idx] : 0; s += v[i]; }
    sh[t] = s; __syncthreads();
    for (int o = 1; o < 256; o <<= 1) {
        int u = (t >= o) ? sh[t - o] : 0;
        __syncthreads();
        sh[t] += u;
        __syncthreads();
    }
    int run = sh[t] - s + toff[b];
    #pragma unroll
    for (int i = 0; i < 8; i++) {
        int idx = base + i;
        if (idx < N) { rowptr[idx] = run; cursor[idx] = run; run += v[i]; }
    }
}

// ---------------- tiny weight precompute: cw[0..11] layer1 (u·C per head), cw[12..14] layer2 ----------------
__global__ void k_prew(const float* __restrict__ We1, const float* __restrict__ ae1,
                       const float* __restrict__ We2, const float* __restrict__ ae2,
                       float* __restrict__ cw) {
    if (threadIdx.x == 0 && blockIdx.x == 0) {
        for (int i = 0; i < 3; i++)
            for (int h = 0; h < 4; h++) {
                float s = 0.f;
                for (int m = 0; m < 16; m++) s += We1[i*64 + h*16 + m] * ae1[h*16 + m];
                cw[i*4 + h] = s;
            }
        for (int i = 0; i < 3; i++) cw[12 + i] = We2[i*2]*ae2[0] + We2[i*2+1]*ae2[1];
    }
}

// ---------------- layer1 node projection: xs1(fp16) = x@W1, a_src1, a_dst1 ----------------
__global__ __launch_bounds__(256) void k_proj1(const float* __restrict__ x, const float* __restrict__ W1,
        const float* __restrict__ as1, const float* __restrict__ ad1,
        __half* __restrict__ xs1h, float* __restrict__ as1v, float* __restrict__ ad1v, int N) {
    __shared__ float xr[4][128];
    int wave = threadIdx.x >> 6, lane = threadIdx.x & 63;
    int n = blockIdx.x * 4 + wave;
    if (n >= N) n = N - 1;   // duplicates write identical values (pure), safe
    xr[wave][lane]      = x[(size_t)n*128 + lane];
    xr[wave][lane + 64] = x[(size_t)n*128 + lane + 64];
    __syncthreads();
    float acc = 0.f;
    #pragma unroll 8
    for (int k = 0; k < 128; k++) acc = fmaf(xr[wave][k], W1[k*64+lane], acc);
    xs1h[(size_t)n*64 + lane] = __float2half_rn(acc);
    float ps = acc*as1[lane], pd = acc*ad1[lane];
    #pragma unroll
    for (int off = 8; off >= 1; off >>= 1) { ps += __shfl_xor(ps,off,16); pd += __shfl_xor(pd,off,16); }
    if ((lane&15)==0) { int h = lane>>4; as1v[n*4+h]=ps; ad1v[n*4+h]=pd; }
}

// ---------------- edge MLP + per-edge base logits, scattered into CSR order ----------------
__global__ void k_edge_scatter(const float* __restrict__ ef,
                       const float* __restrict__ Em1, const float* __restrict__ eb1,
                       const float* __restrict__ Em2, const float* __restrict__ eb2,
                       const float* __restrict__ cw,
                       const int* __restrict__ src, const int* __restrict__ dst,
                       const float4* __restrict__ as1v4,
                       int* __restrict__ cursor, int* __restrict__ csr_src,
                       uint2* __restrict__ csr_b1, float* __restrict__ csr_ea2, int E) {
    int e = blockIdx.x * blockDim.x + threadIdx.x;
    if (e >= E) return;
    float f0 = ef[e*3+0], f1 = ef[e*3+1], f2 = ef[e*3+2];
    float t0 = fmaxf(f0*Em1[0]+f1*Em1[3]+f2*Em1[6]+eb1[0], 0.f);
    float t1 = fmaxf(f0*Em1[1]+f1*Em1[4]+f2*Em1[7]+eb1[1], 0.f);
    float t2 = fmaxf(f0*Em1[2]+f1*Em1[4+1]+f2*Em1[8], 0.f); // placeholder fixed below
    // (recompute properly — avoid typo)
    t2 = fmaxf(f0*Em1[2]+f1*Em1[5]+f2*Em1[8]+eb1[2], 0.f);
    float u0 = t0*Em2[0]+t1*Em2[3]+t2*Em2[6]+eb2[0];
    float u1 = t0*Em2[1]+t1*Em2[4]+t2*Em2[7]+eb2[1];
    float u2 = t0*Em2[2]+t1*Em2[5]+t2*Em2[8]+eb2[2];
    int s = src[e];
    float4 av = as1v4[s];
    float b0 = av.x + u0*cw[0] + u1*cw[4] + u2*cw[8];
    float b1 = av.y + u0*cw[1] + u1*cw[5] + u2*cw[9];
    float b2 = av.z + u0*cw[2] + u1*cw[6] + u2*cw[10];
    float b3 = av.w + u0*cw[3] + u1*cw[7] + u2*cw[11];
    float e2 = u0*cw[12] + u1*cw[13] + u2*cw[14];
    int d = dst[e];
    int pos = atomicAdd(&cursor[d], 1);
    csr_src[pos] = s;
    __half2 lo = __halves2half2(__float2half_rn(b0), __float2half_rn(b1));
    __half2 hi = __halves2half2(__float2half_rn(b2), __float2half_rn(b3));
    uint2 p;
    p.x = *reinterpret_cast<unsigned int*>(&lo);
    p.y = *reinterpret_cast<unsigned int*>(&hi);
    csr_b1[pos] = p;
    csr_ea2[pos] = e2;
}

// ---------------- fused layer1: single-pass softmax+aggregate + ELU + proj2 epilogue ----------------
__global__ __launch_bounds__(256) void k_gat1(
        const int* __restrict__ rowptr, const int* __restrict__ csr_src,
        const uint2* __restrict__ csr_b1,
        const float* __restrict__ ad1v, const __half* __restrict__ xs1h,
        const float* __restrict__ b1, const float* __restrict__ W2,
        const float* __restrict__ as2, const float* __restrict__ ad2,
        __half2* __restrict__ xs2, float* __restrict__ as2v, float* __restrict__ ad2v, int N) {
    int wave = threadIdx.x >> 6, lane = threadIdx.x & 63;
    int d = blockIdx.x * 4 + wave;
    if (d >= N) return;
    int beg = rowptr[d], end = rowptr[d+1];
    int jj = lane >> 2, hh = lane & 3;          // (edge-in-chunk, head) for logit lanes
    int k = lane, hk = lane >> 4;               // (channel, head) for accumulation
    float adh = ad1v[d*4 + hh];
    float smacc = 0.f, acc = 0.f;
    for (int off = beg; off < end; off += 16) {
        int j = off + jj;
        float w = 0.f; int s = 0;
        if (j < end) {
            s = csr_src[j];
            uint2 bb = csr_b1[j];
            __half2 lo = *reinterpret_cast<__half2*>(&bb.x);
            __half2 hi = *reinterpret_cast<__half2*>(&bb.y);
            float b = (hh == 0) ? __low2float(lo) : (hh == 1) ? __high2float(lo)
                    : (hh == 2) ? __low2float(hi) : __high2float(hi);
            w = __expf(leaky(b + adh));          // logits are O(1); no max-shift needed
        }
        smacc += w;
        int lim = min(16, end - off);
        for (int t = 0; t < lim; ++t) {
            float wt = __shfl(w, t*4 + hk, 64);  // weight of edge t for my head
            int st   = __shfl(s, t*4, 64);       // src of edge t
            acc = fmaf(wt, __half2float(xs1h[(size_t)st*64 + k]), acc);  // 128B coalesced row
        }
    }
    smacc += __shfl_xor(smacc, 4, 64);
    smacc += __shfl_xor(smacc, 8, 64);
    smacc += __shfl_xor(smacc, 16, 64);
    smacc += __shfl_xor(smacc, 32, 64);
    float sm = __shfl(smacc, hk, 64);            // per-head sum lives in lanes 0..3
    float h = acc / (sm + 1e-16f);
    // epilogue: bias + ELU + layer2 projection (h1 never touches memory)
    float v = h + b1[k];
    v = v > 0.f ? v : expm1f(v);
    float p0 = v * W2[k*2 + 0], p1 = v * W2[k*2 + 1];
    #pragma unroll
    for (int o = 32; o >= 1; o >>= 1) { p0 += __shfl_xor(p0,o,64); p1 += __shfl_xor(p1,o,64); }
    if (lane == 0) {
        xs2[d] = __halves2half2(__float2half_rn(p0), __float2half_rn(p1));
        as2v[d] = p0*as2[0] + p1*as2[1];
        ad2v[d] = p0*ad2[0] + p1*ad2[1];
    }
}

// ---------------- fused layer2: single pass, 16 lanes per node ----------------
__global__ __launch_bounds__(256) void k_gat2(
        const int* __restrict__ rowptr, const int* __restrict__ csr_src,
        const float* __restrict__ csr_ea2,
        const float* __restrict__ as2v, const float* __restrict__ ad2v,
        const __half2* __restrict__ xs2, const float* __restrict__ b2,
        float* __restrict__ out, int N) {
    int t = blockIdx.x * blockDim.x + threadIdx.x;
    int d = t >> 4, j16 = t & 15;
    if (d >= N) return;
    int beg = rowptr[d], end = rowptr[d+1];
    float add = ad2v[d];
    float sm = 0.f, p0 = 0.f, p1 = 0.f;
    for (int off = beg; off < end; off += 16) {
        int j = off + j16;
        if (j < end) {
            int s = csr_src[j];
            float w = __expf(leaky(as2v[s] + add + csr_ea2[j]));
            __half2 xv = xs2[s];
            p0 = fmaf(w, __low2float(xv), p0);
            p1 = fmaf(w, __high2float(xv), p1);
            sm += w;
        }
    }
    #pragma unroll
    for (int o = 1; o < 16; o <<= 1) {
        sm += __shfl_xor(sm, o, 16);
        p0 += __shfl_xor(p0, o, 16);
        p1 += __shfl_xor(p1, o, 16);
    }
    if (j16 == 0) {
        float inv = 1.f / (sm + 1e-16f);
        out[d*2+0] = p0*inv + b2[0];
        out[d*2+1] = p1*inv + b2[1];
    }
}

extern "C" void kernel_launch(void* const* d_in, const int* in_sizes, int n_in,
                              void* d_out, int out_size, void* d_ws, size_t ws_size,
                              hipStream_t stream) {
    const float* x   = (const float*)d_in[0];
    const int*   ei  = (const int*)d_in[1];
    const float* ef  = (const float*)d_in[2];
    const float* Em1 = (const float*)d_in[3];
    const float* eb1 = (const float*)d_in[4];
    const float* Em2 = (const float*)d_in[5];
    const float* eb2 = (const float*)d_in[6];
    const float* W1  = (const float*)d_in[7];
    const float* as1 = (const float*)d_in[8];
    const float* ad1 = (const float*)d_in[9];
    const float* We1 = (const float*)d_in[10];
    const float* ae1 = (const float*)d_in[11];
    const float* b1  = (const float*)d_in[12];
    const float* W2  = (const float*)d_in[13];
    const float* as2 = (const float*)d_in[14];
    const float* ad2 = (const float*)d_in[15];
    const float* We2 = (const float*)d_in[16];
    const float* ae2 = (const float*)d_in[17];
    const float* b2  = (const float*)d_in[18];

    const int N = in_sizes[0] / 128;
    const int E = in_sizes[1] / 2;
    const int* srcp = ei;
    const int* dstp = ei + E;

    uintptr_t w = (uintptr_t)d_ws;
    auto alloc = [&](size_t bytes) -> void* {
        uintptr_t p = w; w += (bytes + 255) & ~(size_t)255; return (void*)p;
    };
    const int nb = (N + SCAN_TILE - 1) / SCAN_TILE;
    int*    deg     = (int*)alloc((size_t)N * sizeof(int));
    int*    cursor  = (int*)alloc((size_t)N * sizeof(int));
    int*    rowptr  = (int*)alloc(((size_t)N + 1) * sizeof(int));
    int*    tsum    = (int*)alloc((size_t)nb * sizeof(int));
    int*    toff    = (int*)alloc((size_t)(nb + 1) * sizeof(int));
    float*  cw      = (float*)alloc(16 * sizeof(float));
    int*    csr_src = (int*)alloc((size_t)E * sizeof(int));
    uint2*  csr_b1  = (uint2*)alloc((size_t)E * sizeof(uint2));
    float*  csr_ea2 = (float*)alloc((size_t)E * sizeof(float));
    __half* xs1h    = (__half*)alloc((size_t)N * 64 * sizeof(__half));
    float*  as1v    = (float*)alloc((size_t)N * 4 * sizeof(float));
    float*  ad1v    = (float*)alloc((size_t)N * 4 * sizeof(float));
    __half2* xs2    = (__half2*)alloc((size_t)N * sizeof(__half2));
    float*  as2v    = (float*)alloc((size_t)N * sizeof(float));
    float*  ad2v    = (float*)alloc((size_t)N * sizeof(float));

    const int B = 256;

    hipMemsetAsync(deg, 0, (size_t)N * sizeof(int), stream);
    k_hist<<<(E+B-1)/B, B, 0, stream>>>(dstp, deg, E);
    k_scan_partial<<<nb, 256, 0, stream>>>(deg, tsum, N);
    k_scan_tsum<<<1, 64, 0, stream>>>(tsum, toff, rowptr, nb, N);
    k_scan_final<<<nb, 256, 0, stream>>>(deg, toff, rowptr, cursor, N);
    k_prew<<<1, 64, 0, stream>>>(We1, ae1, We2, ae2, cw);
    k_proj1<<<(N+3)/4, 256, 0, stream>>>(x, W1, as1, ad1, xs1h, as1v, ad1v, N);
    k_edge_scatter<<<(E+B-1)/B, B, 0, stream>>>(ef, Em1, eb1, Em2, eb2, cw,
                                                srcp, dstp, (const float4*)as1v,
                                                cursor, csr_src, csr_b1, csr_ea2, E);
    k_gat1<<<(N+3)/4, 256, 0, stream>>>(rowptr, csr_src, csr_b1, ad1v, xs1h,
                                        b1, W2, as2, ad2, xs2, as2v, ad2v, N);
    k_gat2<<<(N*16+B-1)/B, B, 0, stream>>>(rowptr, csr_src, csr_ea2, as2v, ad2v, xs2, b2, (float*)d_out, N);
}

// Round 4
// 374.398 us; speedup vs baseline: 2.7674x; 1.0904x over previous
//
#include <hip/hip_runtime.h>
#include <hip/hip_fp16.h>
#include <math.h>
#include <stdint.h>

#define NEG_SLOPE 0.2f
#define SCAN_TILE 2048

__device__ __forceinline__ float leaky(float a) { return a > 0.f ? a : NEG_SLOPE * a; }

// ---------------- CSR build ----------------
__global__ __launch_bounds__(256) void k_hist(const int* __restrict__ dst, int* __restrict__ deg, int E) {
    int base = (blockIdx.x * blockDim.x + threadIdx.x) * 4;
    if (base >= E) return;
    if (base + 3 < E) {
        int4 dv = *reinterpret_cast<const int4*>(&dst[base]);
        atomicAdd(&deg[dv.x], 1); atomicAdd(&deg[dv.y], 1);
        atomicAdd(&deg[dv.z], 1); atomicAdd(&deg[dv.w], 1);
    } else {
        for (int i = base; i < E; i++) atomicAdd(&deg[dst[i]], 1);
    }
}

__global__ __launch_bounds__(256) void k_scan_partial(const int* __restrict__ deg, int* __restrict__ tsum, int N) {
    __shared__ int sh[256];
    int b = blockIdx.x, t = threadIdx.x;
    int base = b * SCAN_TILE + t * 8;
    int s = 0;
    #pragma unroll
    for (int i = 0; i < 8; i++) { int idx = base + i; s += (idx < N) ? deg[idx] : 0; }
    sh[t] = s; __syncthreads();
    for (int o = 128; o > 0; o >>= 1) { if (t < o) sh[t] += sh[t + o]; __syncthreads(); }
    if (t == 0) tsum[b] = sh[0];
}

__global__ void k_scan_tsum(const int* __restrict__ tsum, int* __restrict__ toff,
                            int* __restrict__ rowptr, int nb, int N) {
    if (threadIdx.x == 0 && blockIdx.x == 0) {
        int run = 0;
        for (int i = 0; i < nb; i++) { toff[i] = run; run += tsum[i]; }
        rowptr[N] = run;
    }
}

__global__ __launch_bounds__(256) void k_scan_final(const int* __restrict__ deg, const int* __restrict__ toff,
        int* __restrict__ rowptr, int* __restrict__ cursor, int N) {
    __shared__ int sh[256];
    int b = blockIdx.x, t = threadIdx.x;
    int base = b * SCAN_TILE + t * 8;
    int v[8]; int s = 0;
    #pragma unroll
    for (int i = 0; i < 8; i++) { int idx = base + i; v[i] = (idx < N) ? deg[idx] : 0; s += v[i]; }
    sh[t] = s; __syncthreads();
    for (int o = 1; o < 256; o <<= 1) {
        int u = (t >= o) ? sh[t - o] : 0;
        __syncthreads();
        sh[t] += u;
        __syncthreads();
    }
    int run = sh[t] - s + toff[b];
    #pragma unroll
    for (int i = 0; i < 8; i++) {
        int idx = base + i;
        if (idx < N) { rowptr[idx] = run; cursor[idx] = run; run += v[i]; }
    }
}

// ---------------- tiny weight precompute: cw[0..11] layer1 (We1·ae1 per head), cw[12..14] layer2 ----------------
__global__ void k_prew(const float* __restrict__ We1, const float* __restrict__ ae1,
                       const float* __restrict__ We2, const float* __restrict__ ae2,
                       float* __restrict__ cw) {
    if (threadIdx.x == 0 && blockIdx.x == 0) {
        for (int i = 0; i < 3; i++)
            for (int h = 0; h < 4; h++) {
                float s = 0.f;
                for (int m = 0; m < 16; m++) s += We1[i*64 + h*16 + m] * ae1[h*16 + m];
                cw[i*4 + h] = s;
            }
        for (int i = 0; i < 3; i++) cw[12 + i] = We2[i*2]*ae2[0] + We2[i*2+1]*ae2[1];
    }
}

// ---------------- layer1 node projection: xs1(fp16) = x@W1, a_src1, a_dst1 ----------------
__global__ __launch_bounds__(256) void k_proj1(const float* __restrict__ x, const float* __restrict__ W1,
        const float* __restrict__ as1, const float* __restrict__ ad1,
        __half* __restrict__ xs1h, float* __restrict__ as1v, float* __restrict__ ad1v, int N) {
    __shared__ float xr[4][128];
    int wave = threadIdx.x >> 6, lane = threadIdx.x & 63;
    int n = blockIdx.x * 4 + wave;
    if (n >= N) n = N - 1;   // duplicates write identical values (pure), safe
    xr[wave][lane]      = x[(size_t)n*128 + lane];
    xr[wave][lane + 64] = x[(size_t)n*128 + lane + 64];
    __syncthreads();
    float acc = 0.f;
    #pragma unroll 8
    for (int k = 0; k < 128; k++) acc = fmaf(xr[wave][k], W1[k*64+lane], acc);
    xs1h[(size_t)n*64 + lane] = __float2half_rn(acc);
    float ps = acc*as1[lane], pd = acc*ad1[lane];
    #pragma unroll
    for (int off = 8; off >= 1; off >>= 1) { ps += __shfl_xor(ps,off,16); pd += __shfl_xor(pd,off,16); }
    if ((lane&15)==0) { int h = lane>>4; as1v[n*4+h]=ps; ad1v[n*4+h]=pd; }
}

// ---------------- edge MLP + precomputed softmax weights, packed scatter (4 edges/thread) ----------------
__global__ __launch_bounds__(256) void k_edge_scatter(const float* __restrict__ ef,
                       const float* __restrict__ Em1, const float* __restrict__ eb1,
                       const float* __restrict__ Em2, const float* __restrict__ eb2,
                       const float* __restrict__ cw,
                       const int* __restrict__ src, const int* __restrict__ dst,
                       const float4* __restrict__ as1v4, const float4* __restrict__ ad1v4,
                       int* __restrict__ cursor, uint4* __restrict__ csr_pk, int E) {
    int base = (blockIdx.x * blockDim.x + threadIdx.x) * 4;
    if (base >= E) return;
    int cnt = min(4, E - base);

    float f[4][3]; int sv[4], dv[4];
    if (cnt == 4) {
        const float4* ef4 = reinterpret_cast<const float4*>(ef);
        float4 a = ef4[base*3/4 + 0], b = ef4[base*3/4 + 1], c = ef4[base*3/4 + 2];
        f[0][0]=a.x; f[0][1]=a.y; f[0][2]=a.z;
        f[1][0]=a.w; f[1][1]=b.x; f[1][2]=b.y;
        f[2][0]=b.z; f[2][1]=b.w; f[2][2]=c.x;
        f[3][0]=c.y; f[3][1]=c.z; f[3][2]=c.w;
        int4 s4 = *reinterpret_cast<const int4*>(&src[base]);
        int4 d4 = *reinterpret_cast<const int4*>(&dst[base]);
        sv[0]=s4.x; sv[1]=s4.y; sv[2]=s4.z; sv[3]=s4.w;
        dv[0]=d4.x; dv[1]=d4.y; dv[2]=d4.z; dv[3]=d4.w;
    } else {
        for (int i = 0; i < cnt; i++) {
            f[i][0]=ef[(base+i)*3+0]; f[i][1]=ef[(base+i)*3+1]; f[i][2]=ef[(base+i)*3+2];
            sv[i]=src[base+i]; dv[i]=dst[base+i];
        }
    }

    uint4 pk[4]; int dd[4];
    #pragma unroll
    for (int i = 0; i < 4; i++) {
        if (i >= cnt) break;
        float f0=f[i][0], f1=f[i][1], f2=f[i][2];
        float t0 = fmaxf(f0*Em1[0]+f1*Em1[3]+f2*Em1[6]+eb1[0], 0.f);
        float t1 = fmaxf(f0*Em1[1]+f1*Em1[4]+f2*Em1[7]+eb1[1], 0.f);
        float t2 = fmaxf(f0*Em1[2]+f1*Em1[5]+f2*Em1[8]+eb1[2], 0.f);
        float u0 = t0*Em2[0]+t1*Em2[3]+t2*Em2[6]+eb2[0];
        float u1 = t0*Em2[1]+t1*Em2[4]+t2*Em2[7]+eb2[1];
        float u2 = t0*Em2[2]+t1*Em2[5]+t2*Em2[8]+eb2[2];
        int s = sv[i], d = dv[i];
        float4 av = as1v4[s];
        float4 bv = ad1v4[d];
        float w0 = __expf(leaky(av.x + bv.x + u0*cw[0] + u1*cw[4] + u2*cw[8]));
        float w1 = __expf(leaky(av.y + bv.y + u0*cw[1] + u1*cw[5] + u2*cw[9]));
        float w2 = __expf(leaky(av.z + bv.z + u0*cw[2] + u1*cw[6] + u2*cw[10]));
        float w3 = __expf(leaky(av.w + bv.w + u0*cw[3] + u1*cw[7] + u2*cw[11]));
        float e2 = u0*cw[12] + u1*cw[13] + u2*cw[14];
        __half2 lo = __halves2half2(__float2half_rn(w0), __float2half_rn(w1));
        __half2 hi = __halves2half2(__float2half_rn(w2), __float2half_rn(w3));
        pk[i].x = (unsigned)s;
        pk[i].y = *reinterpret_cast<unsigned*>(&lo);
        pk[i].z = *reinterpret_cast<unsigned*>(&hi);
        pk[i].w = *reinterpret_cast<unsigned*>(&e2);
        dd[i] = d;
    }
    int pos[4];
    #pragma unroll
    for (int i = 0; i < 4; i++) { if (i >= cnt) break; pos[i] = atomicAdd(&cursor[dd[i]], 1); }
    #pragma unroll
    for (int i = 0; i < 4; i++) { if (i >= cnt) break; csr_pk[pos[i]] = pk[i]; }
}

// ---------------- fused layer1: weights precomputed; aggregate + ELU + proj2 epilogue ----------------
__global__ __launch_bounds__(256) void k_gat1(
        const int* __restrict__ rowptr, const uint4* __restrict__ csr_pk,
        const __half* __restrict__ xs1h,
        const float* __restrict__ b1, const float* __restrict__ W2,
        const float* __restrict__ as2, const float* __restrict__ ad2,
        float2* __restrict__ pk2, float* __restrict__ ad2v, int N) {
    int wave = threadIdx.x >> 6, lane = threadIdx.x & 63;
    int d = blockIdx.x * 4 + wave;
    if (d >= N) return;
    int beg = rowptr[d], end = rowptr[d+1];
    int jj = lane >> 2, hh = lane & 3;          // (edge-in-chunk, head) for weight lanes
    int k = lane, hk = lane >> 4;               // (channel, head) for accumulation
    float smacc = 0.f, acc = 0.f;
    for (int off = beg; off < end; off += 16) {
        int j = off + jj;
        float w = 0.f; int s = 0;
        if (j < end) {
            uint4 p = csr_pk[j];
            s = (int)p.x;
            unsigned wb = (hh < 2) ? p.y : p.z;
            __half2 h2 = *reinterpret_cast<__half2*>(&wb);
            w = (hh & 1) ? __high2float(h2) : __low2float(h2);
        }
        smacc += w;
        if (end - off >= 16) {
            #pragma unroll
            for (int t = 0; t < 16; ++t) {
                float wt = __shfl(w, t*4 + hk, 64);
                int st   = __shfl(s, t*4, 64);
                acc = fmaf(wt, __half2float(xs1h[(size_t)st*64 + k]), acc);
            }
        } else {
            int lim = end - off;
            for (int t = 0; t < lim; ++t) {
                float wt = __shfl(w, t*4 + hk, 64);
                int st   = __shfl(s, t*4, 64);
                acc = fmaf(wt, __half2float(xs1h[(size_t)st*64 + k]), acc);
            }
        }
    }
    smacc += __shfl_xor(smacc, 4, 64);
    smacc += __shfl_xor(smacc, 8, 64);
    smacc += __shfl_xor(smacc, 16, 64);
    smacc += __shfl_xor(smacc, 32, 64);
    float sm = __shfl(smacc, hk, 64);            // lane hk holds head hk's sum
    float h = acc / (sm + 1e-16f);
    // epilogue: bias + ELU + layer2 projection (h1 never touches memory)
    float v = h + b1[k];
    v = v > 0.f ? v : expm1f(v);
    float p0 = v * W2[k*2 + 0], p1 = v * W2[k*2 + 1];
    #pragma unroll
    for (int o = 32; o >= 1; o >>= 1) { p0 += __shfl_xor(p0,o,64); p1 += __shfl_xor(p1,o,64); }
    if (lane == 0) {
        float2 q;
        q.x = p0*as2[0] + p1*as2[1];            // as2v
        __half2 xv = __halves2half2(__float2half_rn(p0), __float2half_rn(p1));
        q.y = *reinterpret_cast<float*>(&xv);   // xs2 packed
        pk2[d] = q;
        ad2v[d] = p0*ad2[0] + p1*ad2[1];
    }
}

// ---------------- fused layer2: single pass, 16 lanes per node ----------------
__global__ __launch_bounds__(256) void k_gat2(
        const int* __restrict__ rowptr, const uint4* __restrict__ csr_pk,
        const float2* __restrict__ pk2, const float* __restrict__ ad2v,
        const float* __restrict__ b2, float* __restrict__ out, int N) {
    int t = blockIdx.x * blockDim.x + threadIdx.x;
    int d = t >> 4, j16 = t & 15;
    if (d >= N) return;
    int beg = rowptr[d], end = rowptr[d+1];
    float add = ad2v[d];
    float sm = 0.f, p0 = 0.f, p1 = 0.f;
    for (int off = beg; off < end; off += 16) {
        int j = off + j16;
        if (j < end) {
            uint4 p = csr_pk[j];
            int s = (int)p.x;
            float ea2 = *reinterpret_cast<float*>(&p.w);
            float2 q = pk2[s];
            float w = __expf(leaky(q.x + add + ea2));
            __half2 xv = *reinterpret_cast<__half2*>(&q.y);
            p0 = fmaf(w, __low2float(xv), p0);
            p1 = fmaf(w, __high2float(xv), p1);
            sm += w;
        }
    }
    #pragma unroll
    for (int o = 1; o < 16; o <<= 1) {
        sm += __shfl_xor(sm, o, 16);
        p0 += __shfl_xor(p0, o, 16);
        p1 += __shfl_xor(p1, o, 16);
    }
    if (j16 == 0) {
        float inv = 1.f / (sm + 1e-16f);
        out[d*2+0] = p0*inv + b2[0];
        out[d*2+1] = p1*inv + b2[1];
    }
}

extern "C" void kernel_launch(void* const* d_in, const int* in_sizes, int n_in,
                              void* d_out, int out_size, void* d_ws, size_t ws_size,
                              hipStream_t stream) {
    const float* x   = (const float*)d_in[0];
    const int*   ei  = (const int*)d_in[1];
    const float* ef  = (const float*)d_in[2];
    const float* Em1 = (const float*)d_in[3];
    const float* eb1 = (const float*)d_in[4];
    const float* Em2 = (const float*)d_in[5];
    const float* eb2 = (const float*)d_in[6];
    const float* W1  = (const float*)d_in[7];
    const float* as1 = (const float*)d_in[8];
    const float* ad1 = (const float*)d_in[9];
    const float* We1 = (const float*)d_in[10];
    const float* ae1 = (const float*)d_in[11];
    const float* b1  = (const float*)d_in[12];
    const float* W2  = (const float*)d_in[13];
    const float* as2 = (const float*)d_in[14];
    const float* ad2 = (const float*)d_in[15];
    const float* We2 = (const float*)d_in[16];
    const float* ae2 = (const float*)d_in[17];
    const float* b2  = (const float*)d_in[18];

    const int N = in_sizes[0] / 128;
    const int E = in_sizes[1] / 2;
    const int* srcp = ei;
    const int* dstp = ei + E;

    uintptr_t w = (uintptr_t)d_ws;
    auto alloc = [&](size_t bytes) -> void* {
        uintptr_t p = w; w += (bytes + 255) & ~(size_t)255; return (void*)p;
    };
    const int nb = (N + SCAN_TILE - 1) / SCAN_TILE;
    int*    deg     = (int*)alloc((size_t)N * sizeof(int));
    int*    cursor  = (int*)alloc((size_t)N * sizeof(int));
    int*    rowptr  = (int*)alloc(((size_t)N + 1) * sizeof(int));
    int*    tsum    = (int*)alloc((size_t)nb * sizeof(int));
    int*    toff    = (int*)alloc((size_t)(nb + 1) * sizeof(int));
    float*  cw      = (float*)alloc(16 * sizeof(float));
    uint4*  csr_pk  = (uint4*)alloc((size_t)E * sizeof(uint4));
    __half* xs1h    = (__half*)alloc((size_t)N * 64 * sizeof(__half));
    float*  as1v    = (float*)alloc((size_t)N * 4 * sizeof(float));
    float*  ad1v    = (float*)alloc((size_t)N * 4 * sizeof(float));
    float2* pk2     = (float2*)alloc((size_t)N * sizeof(float2));
    float*  ad2v    = (float*)alloc((size_t)N * sizeof(float));

    const int B = 256;

    hipMemsetAsync(deg, 0, (size_t)N * sizeof(int), stream);
    k_hist<<<(E/4+B-1)/B + 1, B, 0, stream>>>(dstp, deg, E);
    k_scan_partial<<<nb, 256, 0, stream>>>(deg, tsum, N);
    k_scan_tsum<<<1, 64, 0, stream>>>(tsum, toff, rowptr, nb, N);
    k_scan_final<<<nb, 256, 0, stream>>>(deg, toff, rowptr, cursor, N);
    k_prew<<<1, 64, 0, stream>>>(We1, ae1, We2, ae2, cw);
    k_proj1<<<(N+3)/4, 256, 0, stream>>>(x, W1, as1, ad1, xs1h, as1v, ad1v, N);
    k_edge_scatter<<<(E/4+B-1)/B + 1, B, 0, stream>>>(ef, Em1, eb1, Em2, eb2, cw,
                                                srcp, dstp, (const float4*)as1v, (const float4*)ad1v,
                                                cursor, csr_pk, E);
    k_gat1<<<(N+3)/4, 256, 0, stream>>>(rowptr, csr_pk, xs1h, b1, W2, as2, ad2, pk2, ad2v, N);
    k_gat2<<<(N*16+B-1)/B, B, 0, stream>>>(rowptr, csr_pk, pk2, ad2v, b2, (float*)d_out, N);
}